// Round 8
// baseline (182.176 us; speedup 1.0000x reference)
//
#include <hip/hip_runtime.h>
#include <hip/hip_bf16.h>

typedef __attribute__((ext_vector_type(8))) short bf16x8;
typedef __attribute__((ext_vector_type(4))) float f32x4;

__device__ __forceinline__ unsigned short f2bf(float f) {
    unsigned x = __float_as_uint(f);
    unsigned r = (x + 0x7FFF + ((x >> 16) & 1)) >> 16;   // RNE
    return (unsigned short)r;
}
__device__ __forceinline__ bf16x8 cvt8(const float* __restrict__ p) {
    bf16x8 r;
#pragma unroll
    for (int j = 0; j < 8; ++j) r[j] = (short)f2bf(p[j]);
    return r;
}
__device__ __forceinline__ unsigned pack_relu_bf16(unsigned yv, unsigned zv) {
    float lo = fmaxf(__uint_as_float(yv << 16) + __uint_as_float(zv << 16), 0.0f);
    float hi = fmaxf(__uint_as_float(yv & 0xFFFF0000u) + __uint_as_float(zv & 0xFFFF0000u), 0.0f);
    __hip_bfloat162 p = __float22bfloat162_rn(float2{lo, hi});
    return *(unsigned*)&p;
}

// ---------------- kernel A: weight prep (block 0) + segment bounds (rest) -------
__global__ void prep_bounds_k(const float* __restrict__ w1,
                              const float* __restrict__ w2,
                              const int* __restrict__ segs,
                              unsigned short* __restrict__ w1t,
                              unsigned short* __restrict__ w2t,
                              int* __restrict__ seg_off, int N, int E) {
    int t = threadIdx.x;
    if (blockIdx.x == 0) {
        for (int i = t; i < 128 * 64; i += 256) {
            int k = i >> 6, n = i & 63;
            w1t[n * 128 + k] = f2bf(w1[i]);
        }
        for (int i = t; i < 64 * 64; i += 256) {
            int k = i >> 6, n = i & 63;
            w2t[n * 64 + k] = f2bf(w2[i]);
        }
    } else {
        int idx = (blockIdx.x - 1) * 256 + t;
        if (idx > N) return;
        int l = 0, r = E;
        while (l < r) { int mid = (l + r) >> 1; if (segs[mid] < idx) l = mid + 1; else r = mid; }
        seg_off[idx] = l;
    }
}

// ---------------- kernel B: build YU table + z ----------------------------------
// [0,yblocks): row v -> YU[v] = [ Y[v]=u2e[v]@W1_top (64 bf16) | u2e[v] bf16 (64) ]
// [yblocks,..): z[n] = u2e[nodes[n]]@W1_bot + b1 (bf16)
__launch_bounds__(256)
__global__ void conv_yu_z_k(const float* __restrict__ u2e,
                            const int* __restrict__ nodes,
                            const unsigned short* __restrict__ w1t,
                            const float* __restrict__ b1f,
                            unsigned short* __restrict__ YU,
                            unsigned short* __restrict__ z,
                            int V, int N, int yblocks) {
    const int wid = threadIdx.x >> 6;
    const int lane = threadIdx.x & 63;
    const int q = lane >> 4;
    const int m15 = lane & 15;

    if ((int)blockIdx.x < yblocks) {
        const int wbase = (blockIdx.x * 4 + wid) * 16;
        if (wbase >= V) return;
        int row = min(wbase + m15, V - 1);
        const float* p = u2e + (long)row * 64;
        bf16x8 a0 = cvt8(p + q * 8);
        bf16x8 a1 = cvt8(p + 32 + q * 8);
        if (wbase + m15 < V) {                 // U half of the row
            *(bf16x8*)(YU + (long)row * 128 + 64 + q * 8) = a0;
            *(bf16x8*)(YU + (long)row * 128 + 96 + q * 8) = a1;
        }
        f32x4 acc[4];
#pragma unroll
        for (int b = 0; b < 4; ++b) {
            acc[b] = (f32x4){0.f, 0.f, 0.f, 0.f};
            const bf16x8* wrow = (const bf16x8*)(w1t + (b * 16 + m15) * 128);
            acc[b] = __builtin_amdgcn_mfma_f32_16x16x32_bf16(a0, wrow[0 + q], acc[b], 0, 0, 0);
            acc[b] = __builtin_amdgcn_mfma_f32_16x16x32_bf16(a1, wrow[4 + q], acc[b], 0, 0, 0);
        }
#pragma unroll
        for (int b = 0; b < 4; ++b)
#pragma unroll
            for (int r = 0; r < 4; ++r) {
                int rr = wbase + q * 4 + r;
                if (rr < V) YU[(long)rr * 128 + b * 16 + m15] = f2bf(acc[b][r]);  // Y half
            }
    } else {
        const int wbase = (((int)blockIdx.x - yblocks) * 4 + wid) * 16;
        if (wbase >= N) return;
        int nd = nodes[min(wbase + m15, N - 1)];
        const float* p = u2e + (long)nd * 64;
        bf16x8 a0 = cvt8(p + q * 8);
        bf16x8 a1 = cvt8(p + 32 + q * 8);
        f32x4 acc[4];
#pragma unroll
        for (int b = 0; b < 4; ++b) {
            float bv = b1f[b * 16 + m15];
            acc[b] = (f32x4){bv, bv, bv, bv};
            const bf16x8* wrow = (const bf16x8*)(w1t + (b * 16 + m15) * 128);
            acc[b] = __builtin_amdgcn_mfma_f32_16x16x32_bf16(a0, wrow[8 + q], acc[b], 0, 0, 0);
            acc[b] = __builtin_amdgcn_mfma_f32_16x16x32_bf16(a1, wrow[12 + q], acc[b], 0, 0, 0);
        }
#pragma unroll
        for (int b = 0; b < 4; ++b)
#pragma unroll
            for (int r = 0; r < 4; ++r) {
                int rr = wbase + q * 4 + r;
                if (rr < N) z[(long)rr * 64 + b * 16 + m15] = f2bf(acc[b][r]);
            }
    }
}

// ---------------- kernel C (fused): wave-per-node MLP + softmax + aggregation ---
// Per 16-edge group: gather YU row once; h1=relu(Y+z) in A-layout regs; MFMA
// layer2; layer3 butterfly over the 16 cols (all lanes get row sums); cross-q
// shfl routes each lane its OWN edge's logit; exp; accumulate ex*U into per-lane
// channel partials. Normalize once per node. No LDS, no barriers.
__launch_bounds__(256)
__global__ void node_k(const int* __restrict__ seg_off,
                       const int* __restrict__ neigh,
                       const unsigned short* __restrict__ YU,
                       const unsigned short* __restrict__ zb,
                       const unsigned short* __restrict__ w2t,
                       const float* __restrict__ b2f,
                       const float* __restrict__ w3f, const float* __restrict__ b3f,
                       float* __restrict__ out, int N) {
    const int wid = threadIdx.x >> 6;
    const int lane = threadIdx.x & 63;
    const int q = lane >> 4;
    const int m15 = lane & 15;
    const int n = blockIdx.x * 4 + wid;
    if (n >= N) return;
    const int lo = seg_off[n];
    const int hi = seg_off[n + 1];

    // node z row (A-layout frags; broadcast loads across m15)
    const unsigned short* zr = zb + (long)n * 64;
    bf16x8 z0 = *(const bf16x8*)(zr + q * 8);
    bf16x8 z1 = *(const bf16x8*)(zr + 32 + q * 8);

    // hoisted layer-2 B-frags + per-lane weights
    bf16x8 wb0[4], wb1[4];
    float bv[4], w3l[4];
#pragma unroll
    for (int b = 0; b < 4; ++b) {
        const bf16x8* wrow = (const bf16x8*)(w2t + (b * 16 + m15) * 64);
        wb0[b] = wrow[0 + q];
        wb1[b] = wrow[4 + q];
        bv[b] = b2f[b * 16 + m15];
        w3l[b] = w3f[b * 16 + m15];
    }
    const float b3v = b3f[0];
    const int srcl = ((m15 >> 2) << 4) | m15;   // cross-q route for own-edge logit

    float a[16];
#pragma unroll
    for (int j = 0; j < 16; ++j) a[j] = 0.0f;
    float s = 0.0f;

    for (int cs = lo; cs < hi; cs += 32) {
#pragma unroll
        for (int g = 0; g < 2; ++g) {
            const int gb = cs + g * 16;
            if (gb < hi) {                       // wave-uniform
                const int e = gb + m15;
                const bool val = e < hi;
                const int ec = val ? e : hi - 1;
                const int vi = neigh[ec];
                const unsigned short* row = YU + (long)vi * 128;
                bf16x8 y0 = *(const bf16x8*)(row + q * 8);
                bf16x8 y1 = *(const bf16x8*)(row + 32 + q * 8);
                bf16x8 u0 = *(const bf16x8*)(row + 64 + q * 16);
                bf16x8 u1 = *(const bf16x8*)(row + 72 + q * 16);

                bf16x8 h0, h1;
#pragma unroll
                for (int j = 0; j < 4; ++j) {
                    ((unsigned*)&h0)[j] = pack_relu_bf16(((unsigned*)&y0)[j], ((unsigned*)&z0)[j]);
                    ((unsigned*)&h1)[j] = pack_relu_bf16(((unsigned*)&y1)[j], ((unsigned*)&z1)[j]);
                }

                f32x4 acc[4];
#pragma unroll
                for (int b = 0; b < 4; ++b) {
                    acc[b] = (f32x4){bv[b], bv[b], bv[b], bv[b]};
                    acc[b] = __builtin_amdgcn_mfma_f32_16x16x32_bf16(h0, wb0[b], acc[b], 0, 0, 0);
                    acc[b] = __builtin_amdgcn_mfma_f32_16x16x32_bf16(h1, wb1[b], acc[b], 0, 0, 0);
                }

                // layer 3: per-row logits, butterfly over the 16 cols (m15 dim)
                float vr[4];
#pragma unroll
                for (int r = 0; r < 4; ++r) {
                    float v = 0.0f;
#pragma unroll
                    for (int b = 0; b < 4; ++b) v += fmaxf(acc[b][r], 0.0f) * w3l[b];
                    v += __shfl_xor(v, 1);
                    v += __shfl_xor(v, 2);
                    v += __shfl_xor(v, 4);
                    v += __shfl_xor(v, 8);
                    vr[r] = v;                   // row gb + q*4 + r, all 16 lanes of this q
                }
                // route: this lane's own edge (row m15) lives in q-group m15>>2, reg m15&3
                float tmp = (m15 & 2) ? ((m15 & 1) ? vr[3] : vr[2])
                                      : ((m15 & 1) ? vr[1] : vr[0]);
                float myv = __shfl(tmp, srcl);
                float exg = val ? __expf(myv + b3v) : 0.0f;
                if (q == 0) s += exg;

                const unsigned* ud0 = (const unsigned*)&u0;
                const unsigned* ud1 = (const unsigned*)&u1;
#pragma unroll
                for (int j = 0; j < 4; ++j) {
                    a[2 * j]      = fmaf(exg, __uint_as_float(ud0[j] << 16), a[2 * j]);
                    a[2 * j + 1]  = fmaf(exg, __uint_as_float(ud0[j] & 0xFFFF0000u), a[2 * j + 1]);
                    a[8 + 2 * j]  = fmaf(exg, __uint_as_float(ud1[j] << 16), a[8 + 2 * j]);
                    a[9 + 2 * j]  = fmaf(exg, __uint_as_float(ud1[j] & 0xFFFF0000u), a[9 + 2 * j]);
                }
            }
        }
    }

    // fold partials over the 16 edge-lanes (never crosses q)
#pragma unroll
    for (int msk = 1; msk <= 8; msk <<= 1) {
        s += __shfl_xor(s, msk);
#pragma unroll
        for (int j = 0; j < 16; ++j) a[j] += __shfl_xor(a[j], msk);
    }
    s = __shfl(s, m15);                          // broadcast total from q0 group
    const float inv = 1.0f / fmaxf(s, 1e-9f);
    if (m15 == 0) {                              // 4 lanes, ch q*16..q*16+15
        float* op = out + (long)n * 64 + q * 16;
#pragma unroll
        for (int j = 0; j < 4; ++j) {
            float4 o = {a[4 * j] * inv, a[4 * j + 1] * inv,
                        a[4 * j + 2] * inv, a[4 * j + 3] * inv};
            *(float4*)(op + 4 * j) = o;
        }
    }
}

// ---------------- tier-3 fallback (tiny ws): f32 direct ------------------------
__launch_bounds__(256)
__global__ void logits_fb_k(const int* __restrict__ nodes,
                            const int* __restrict__ neigh,
                            const int* __restrict__ segs,
                            const float* __restrict__ u2e,
                            const unsigned short* __restrict__ w1t,
                            const unsigned short* __restrict__ w2t,
                            const float* __restrict__ b1f, const float* __restrict__ b2f,
                            const float* __restrict__ w3f, const float* __restrict__ b3f,
                            float* __restrict__ ex, int E) {
    __shared__ __align__(16) unsigned short h1buf[4][16 * 72];
    const int wid = threadIdx.x >> 6;
    const int lane = threadIdx.x & 63;
    const int q = lane >> 4;
    const int m15 = lane & 15;
    const long base = ((long)blockIdx.x * 4 + wid) * 16;
    long ee0 = base + m15;
    int e = (int)(ee0 < E ? ee0 : (long)E - 1);
    int ni = neigh[e];
    int ctr = nodes[segs[e]];
    const float* eu = u2e + (long)ni * 64;
    const float* ur = u2e + (long)ctr * 64;
    bf16x8 a0 = cvt8(eu + q * 8), a1 = cvt8(eu + 32 + q * 8);
    bf16x8 a2 = cvt8(ur + q * 8), a3 = cvt8(ur + 32 + q * 8);
    f32x4 acc[4];
#pragma unroll
    for (int b = 0; b < 4; ++b) {
        float bvv = b1f[b * 16 + m15];
        acc[b] = (f32x4){bvv, bvv, bvv, bvv};
        const bf16x8* wrow = (const bf16x8*)(w1t + (b * 16 + m15) * 128);
        acc[b] = __builtin_amdgcn_mfma_f32_16x16x32_bf16(a0, wrow[0 + q], acc[b], 0, 0, 0);
        acc[b] = __builtin_amdgcn_mfma_f32_16x16x32_bf16(a1, wrow[4 + q], acc[b], 0, 0, 0);
        acc[b] = __builtin_amdgcn_mfma_f32_16x16x32_bf16(a2, wrow[8 + q], acc[b], 0, 0, 0);
        acc[b] = __builtin_amdgcn_mfma_f32_16x16x32_bf16(a3, wrow[12 + q], acc[b], 0, 0, 0);
    }
#pragma unroll
    for (int b = 0; b < 4; ++b)
#pragma unroll
        for (int r = 0; r < 4; ++r)
            h1buf[wid][(q * 4 + r) * 72 + b * 16 + m15] = f2bf(fmaxf(acc[b][r], 0.0f));
    const unsigned short* hrow = &h1buf[wid][m15 * 72];
    bf16x8 h0 = *(const bf16x8*)(hrow + q * 8);
    bf16x8 h1 = *(const bf16x8*)(hrow + 32 + q * 8);
    f32x4 acc2[4];
#pragma unroll
    for (int b = 0; b < 4; ++b) {
        float bvv = b2f[b * 16 + m15];
        acc2[b] = (f32x4){bvv, bvv, bvv, bvv};
        const bf16x8* wrow = (const bf16x8*)(w2t + (b * 16 + m15) * 64);
        acc2[b] = __builtin_amdgcn_mfma_f32_16x16x32_bf16(h0, wrow[0 + q], acc2[b], 0, 0, 0);
        acc2[b] = __builtin_amdgcn_mfma_f32_16x16x32_bf16(h1, wrow[4 + q], acc2[b], 0, 0, 0);
    }
    float b3v = b3f[0];
#pragma unroll
    for (int r = 0; r < 4; ++r) {
        float v = 0.0f;
#pragma unroll
        for (int b = 0; b < 4; ++b) v += fmaxf(acc2[b][r], 0.0f) * w3f[b * 16 + m15];
        v += __shfl_xor(v, 1);
        v += __shfl_xor(v, 2);
        v += __shfl_xor(v, 4);
        v += __shfl_xor(v, 8);
        long ee = base + q * 4 + r;
        if (m15 == r && ee < E) ex[ee] = __expf(v + b3v);
    }
}

__launch_bounds__(256)
__global__ void aggw_fb_k(const int* __restrict__ seg_off,
                          const int* __restrict__ neigh,
                          const float* __restrict__ u2e,
                          const float* __restrict__ ex,
                          float* __restrict__ out, int N) {
    const int wid = threadIdx.x >> 6;
    const int lane = threadIdx.x & 63;
    const int n = blockIdx.x * 4 + wid;
    if (n >= N) return;
    const int lo = seg_off[n];
    const int hi = seg_off[n + 1];
    const int slot = lane >> 3;
    const int cl = lane & 7;
    float a[8] = {0.f, 0.f, 0.f, 0.f, 0.f, 0.f, 0.f, 0.f};
    float s = 0.0f;
    for (int e = lo + slot; e < hi; e += 8) {
        float w = ex[e];
        int vi = neigh[e];
        s += w;
        const float* row = u2e + (long)vi * 64 + cl * 8;
        float4 v0 = *(const float4*)row;
        float4 v1 = *(const float4*)(row + 4);
        a[0] = fmaf(w, v0.x, a[0]); a[1] = fmaf(w, v0.y, a[1]);
        a[2] = fmaf(w, v0.z, a[2]); a[3] = fmaf(w, v0.w, a[3]);
        a[4] = fmaf(w, v1.x, a[4]); a[5] = fmaf(w, v1.y, a[5]);
        a[6] = fmaf(w, v1.z, a[6]); a[7] = fmaf(w, v1.w, a[7]);
    }
#pragma unroll
    for (int msk = 8; msk <= 32; msk <<= 1) {
        s += __shfl_xor(s, msk);
#pragma unroll
        for (int j = 0; j < 8; ++j) a[j] += __shfl_xor(a[j], msk);
    }
    if (slot == 0) {
        float inv = 1.0f / fmaxf(s, 1e-9f);
        float4 o0 = {a[0] * inv, a[1] * inv, a[2] * inv, a[3] * inv};
        float4 o1 = {a[4] * inv, a[5] * inv, a[6] * inv, a[7] * inv};
        float* op = out + (long)n * 64 + cl * 8;
        *(float4*)op = o0;
        *(float4*)(op + 4) = o1;
    }
}

extern "C" void kernel_launch(void* const* d_in, const int* in_sizes, int n_in,
                              void* d_out, int out_size, void* d_ws, size_t ws_size,
                              hipStream_t stream) {
    const int* nodes = (const int*)d_in[0];
    const int* neigh = (const int*)d_in[1];
    const int* segs  = (const int*)d_in[2];
    const float* u2e = (const float*)d_in[3];
    const float* w1  = (const float*)d_in[4];
    const float* b1  = (const float*)d_in[5];
    const float* w2  = (const float*)d_in[6];
    const float* b2  = (const float*)d_in[7];
    const float* w3  = (const float*)d_in[8];
    const float* b3  = (const float*)d_in[9];
    const int N = in_sizes[0];
    const int E = in_sizes[1];
    const long VD = in_sizes[3];
    const int V = (int)(VD / 64);

    char* ws = (char*)d_ws;
    size_t off = 0;
    auto alloc = [&](size_t bytes) { char* p = ws + off; off = (off + bytes + 255) & ~(size_t)255; return p; };
    float* ex = (float*)alloc((size_t)E * 4);                    // tier-3 only
    int* seg_off = (int*)alloc((size_t)(N + 1) * 4);
    unsigned short* w1t = (unsigned short*)alloc(128 * 64 * 2);
    unsigned short* w2t = (unsigned short*)alloc(64 * 64 * 2);
    unsigned short* YU = (unsigned short*)alloc((size_t)V * 256); // V x 128 bf16
    unsigned short* zb = (unsigned short*)alloc((size_t)N * 64 * 2);
    size_t need_t1 = off;

    float* out = (float*)d_out;

    const int pbblocks = 1 + (N + 256) / 256;
    prep_bounds_k<<<pbblocks, 256, 0, stream>>>(w1, w2, segs, w1t, w2t, seg_off, N, E);

    const int yblocks = ((V + 15) / 16 + 3) / 4;
    const int zblocks = ((N + 15) / 16 + 3) / 4;
    const int nblocks = (N + 3) / 4;

    if (ws_size >= need_t1) {
        conv_yu_z_k<<<yblocks + zblocks, 256, 0, stream>>>(
            u2e, nodes, w1t, b1, YU, zb, V, N, yblocks);
        node_k<<<nblocks, 256, 0, stream>>>(seg_off, neigh, YU, zb, w2t,
                                            b2, w3, b3, out, N);
    } else {
        const int blocks1 = ((E + 15) / 16 + 3) / 4;
        logits_fb_k<<<blocks1, 256, 0, stream>>>(nodes, neigh, segs, u2e, w1t, w2t,
                                                 b1, b2, w3, b3, ex, E);
        aggw_fb_k<<<nblocks, 256, 0, stream>>>(seg_off, neigh, u2e, ex, out, N);
    }
}

// Round 9
// 171.625 us; speedup vs baseline: 1.0615x; 1.0615x over previous
//
#include <hip/hip_runtime.h>
#include <hip/hip_bf16.h>

typedef __attribute__((ext_vector_type(8))) short bf16x8;
typedef __attribute__((ext_vector_type(4))) float f32x4;

__device__ __forceinline__ unsigned short f2bf(float f) {
    unsigned x = __float_as_uint(f);
    unsigned r = (x + 0x7FFF + ((x >> 16) & 1)) >> 16;   // RNE
    return (unsigned short)r;
}
__device__ __forceinline__ bf16x8 cvt8(const float* __restrict__ p) {
    bf16x8 r;
#pragma unroll
    for (int j = 0; j < 8; ++j) r[j] = (short)f2bf(p[j]);
    return r;
}
__device__ __forceinline__ unsigned pack_relu_bf16(unsigned yv, unsigned zv) {
    float lo = fmaxf(__uint_as_float(yv << 16) + __uint_as_float(zv << 16), 0.0f);
    float hi = fmaxf(__uint_as_float(yv & 0xFFFF0000u) + __uint_as_float(zv & 0xFFFF0000u), 0.0f);
    __hip_bfloat162 p = __float22bfloat162_rn(float2{lo, hi});
    return *(unsigned*)&p;
}

// ---------------- kernel A: weight prep (block 0) + segment bounds (rest) -------
__global__ void prep_bounds_k(const float* __restrict__ w1,
                              const float* __restrict__ w2,
                              const int* __restrict__ segs,
                              unsigned short* __restrict__ w1t,
                              unsigned short* __restrict__ w2t,
                              int* __restrict__ seg_off, int N, int E) {
    int t = threadIdx.x;
    if (blockIdx.x == 0) {
        for (int i = t; i < 128 * 64; i += 256) {
            int k = i >> 6, n = i & 63;
            w1t[n * 128 + k] = f2bf(w1[i]);
        }
        for (int i = t; i < 64 * 64; i += 256) {
            int k = i >> 6, n = i & 63;
            w2t[n * 64 + k] = f2bf(w2[i]);
        }
    } else {
        int idx = (blockIdx.x - 1) * 256 + t;
        if (idx > N) return;
        int l = 0, r = E;
        while (l < r) { int mid = (l + r) >> 1; if (segs[mid] < idx) l = mid + 1; else r = mid; }
        seg_off[idx] = l;
    }
}

// ---------------- kernel B: [0,yblocks): u2e->bf16 + Y = u2e@W1_top ------------
//                  [yblocks,..): z[n] = u2e[nodes[n]]@W1_bot + b1   (both bf16)
template <bool BF>
__launch_bounds__(256)
__global__ void conv_y_z_k(const float* __restrict__ u2e,
                           const int* __restrict__ nodes,
                           const unsigned short* __restrict__ w1t,
                           const float* __restrict__ b1f,
                           unsigned short* __restrict__ u2ebf,
                           unsigned short* __restrict__ Y,
                           unsigned short* __restrict__ z,
                           int V, int N, int yblocks) {
    const int wid = threadIdx.x >> 6;
    const int lane = threadIdx.x & 63;
    const int q = lane >> 4;
    const int m15 = lane & 15;

    if ((int)blockIdx.x < yblocks) {
        const int wbase = (blockIdx.x * 4 + wid) * 16;
        if (wbase >= V) return;
        int row = min(wbase + m15, V - 1);
        const float* p = u2e + (long)row * 64;
        bf16x8 a0 = cvt8(p + q * 8);
        bf16x8 a1 = cvt8(p + 32 + q * 8);
        if (BF && wbase + m15 < V) {
            *(bf16x8*)(u2ebf + (long)row * 64 + q * 8) = a0;
            *(bf16x8*)(u2ebf + (long)row * 64 + 32 + q * 8) = a1;
        }
        f32x4 acc[4];
#pragma unroll
        for (int b = 0; b < 4; ++b) {
            acc[b] = (f32x4){0.f, 0.f, 0.f, 0.f};
            const bf16x8* wrow = (const bf16x8*)(w1t + (b * 16 + m15) * 128);
            acc[b] = __builtin_amdgcn_mfma_f32_16x16x32_bf16(a0, wrow[0 + q], acc[b], 0, 0, 0);
            acc[b] = __builtin_amdgcn_mfma_f32_16x16x32_bf16(a1, wrow[4 + q], acc[b], 0, 0, 0);
        }
#pragma unroll
        for (int b = 0; b < 4; ++b)
#pragma unroll
            for (int r = 0; r < 4; ++r) {
                int rr = wbase + q * 4 + r;
                if (rr < V) Y[(long)rr * 64 + b * 16 + m15] = f2bf(acc[b][r]);
            }
    } else {
        const int wbase = (((int)blockIdx.x - yblocks) * 4 + wid) * 16;
        if (wbase >= N) return;
        int nd = nodes[min(wbase + m15, N - 1)];
        const float* p = u2e + (long)nd * 64;
        bf16x8 a0 = cvt8(p + q * 8);
        bf16x8 a1 = cvt8(p + 32 + q * 8);
        f32x4 acc[4];
#pragma unroll
        for (int b = 0; b < 4; ++b) {
            float bv = b1f[b * 16 + m15];
            acc[b] = (f32x4){bv, bv, bv, bv};
            const bf16x8* wrow = (const bf16x8*)(w1t + (b * 16 + m15) * 128);
            acc[b] = __builtin_amdgcn_mfma_f32_16x16x32_bf16(a0, wrow[8 + q], acc[b], 0, 0, 0);
            acc[b] = __builtin_amdgcn_mfma_f32_16x16x32_bf16(a1, wrow[12 + q], acc[b], 0, 0, 0);
        }
#pragma unroll
        for (int b = 0; b < 4; ++b)
#pragma unroll
            for (int r = 0; r < 4; ++r) {
                int rr = wbase + q * 4 + r;
                if (rr < N) z[(long)rr * 64 + b * 16 + m15] = f2bf(acc[b][r]);
            }
    }
}

// ---------------- kernel 1: per-edge MLP, 32 edges/wave (2x16 groups) -----------
__launch_bounds__(256)
__global__ void logits2_k(const int* __restrict__ neigh,
                          const int* __restrict__ segs,
                          const unsigned short* __restrict__ Y,
                          const unsigned short* __restrict__ z,
                          const unsigned short* __restrict__ w2t,
                          const float* __restrict__ b2f,
                          const float* __restrict__ w3f, const float* __restrict__ b3f,
                          float* __restrict__ ex, int E) {
    const int wid = threadIdx.x >> 6;
    const int lane = threadIdx.x & 63;
    const int q = lane >> 4;
    const int m15 = lane & 15;
    const long base = ((long)blockIdx.x * 4 + wid) * 32;
    if (base >= E) return;

    int vi[2], sg[2];
#pragma unroll
    for (int g = 0; g < 2; ++g) {
        long e = base + g * 16 + m15;
        int ec = (int)(e < E ? e : (long)E - 1);
        vi[g] = neigh[ec];
        sg[g] = segs[ec];
    }
    bf16x8 y0[2], y1[2], zz0[2], zz1[2];
#pragma unroll
    for (int g = 0; g < 2; ++g) {
        const unsigned short* yr = Y + (long)vi[g] * 64;
        y0[g] = *(const bf16x8*)(yr + q * 8);
        y1[g] = *(const bf16x8*)(yr + 32 + q * 8);
        const unsigned short* zr = z + (long)sg[g] * 64;
        zz0[g] = *(const bf16x8*)(zr + q * 8);
        zz1[g] = *(const bf16x8*)(zr + 32 + q * 8);
    }

    f32x4 acc[2][4];
#pragma unroll
    for (int g = 0; g < 2; ++g) {
        bf16x8 h0, h1;
#pragma unroll
        for (int j = 0; j < 4; ++j) {
            ((unsigned*)&h0)[j] = pack_relu_bf16(((unsigned*)&y0[g])[j], ((unsigned*)&zz0[g])[j]);
            ((unsigned*)&h1)[j] = pack_relu_bf16(((unsigned*)&y1[g])[j], ((unsigned*)&zz1[g])[j]);
        }
#pragma unroll
        for (int b = 0; b < 4; ++b) {
            float bv = b2f[b * 16 + m15];
            acc[g][b] = (f32x4){bv, bv, bv, bv};
            const bf16x8* wrow = (const bf16x8*)(w2t + (b * 16 + m15) * 64);
            acc[g][b] = __builtin_amdgcn_mfma_f32_16x16x32_bf16(h0, wrow[0 + q], acc[g][b], 0, 0, 0);
            acc[g][b] = __builtin_amdgcn_mfma_f32_16x16x32_bf16(h1, wrow[4 + q], acc[g][b], 0, 0, 0);
        }
    }

    const float b3v = b3f[0];
#pragma unroll
    for (int g = 0; g < 2; ++g)
#pragma unroll
        for (int r = 0; r < 4; ++r) {
            float v = 0.0f;
#pragma unroll
            for (int b = 0; b < 4; ++b) v += fmaxf(acc[g][b][r], 0.0f) * w3f[b * 16 + m15];
            v += __shfl_xor(v, 1);
            v += __shfl_xor(v, 2);
            v += __shfl_xor(v, 4);
            v += __shfl_xor(v, 8);
            long ee = base + g * 16 + q * 4 + r;
            if (m15 == r && ee < E) ex[ee] = __expf(v + b3v);
        }
}

// ---------------- kernel 2: wave-per-node weighted segment sum, 16 slots --------
// lane = slot(0..15)*4 + cl(0..3); slot -> edge stride 16, cl -> 16 channels (32B).
// 16 row-gathers in flight per wave. Fold over slot bits (masks 4..32).
template <bool BF>
__launch_bounds__(256)
__global__ void aggw_k(const int* __restrict__ seg_off,
                       const int* __restrict__ neigh,
                       const unsigned short* __restrict__ u2ebf,
                       const float* __restrict__ u2e,
                       const float* __restrict__ ex,
                       float* __restrict__ out, int N) {
    const int wid = threadIdx.x >> 6;
    const int lane = threadIdx.x & 63;
    const int n = blockIdx.x * 4 + wid;
    if (n >= N) return;
    const int lo = seg_off[n];
    const int hi = seg_off[n + 1];
    const int slot = lane >> 2;     // 0..15
    const int cl = lane & 3;        // 0..3 -> channels cl*16 .. cl*16+15

    float a[16];
#pragma unroll
    for (int j = 0; j < 16; ++j) a[j] = 0.0f;
    float s = 0.0f;

    for (int e = lo + slot; e < hi; e += 16) {
        float w = ex[e];
        int vi = neigh[e];
        s += w;                     // every cl lane counts the same total; folds per-cl
        if constexpr (BF) {
            const unsigned short* row = u2ebf + (long)vi * 64 + cl * 16;
            bf16x8 v0 = *(const bf16x8*)row;
            bf16x8 v1 = *(const bf16x8*)(row + 8);
            const unsigned* d0 = (const unsigned*)&v0;
            const unsigned* d1 = (const unsigned*)&v1;
#pragma unroll
            for (int j = 0; j < 4; ++j) {
                a[2 * j]     = fmaf(w, __uint_as_float(d0[j] << 16), a[2 * j]);
                a[2 * j + 1] = fmaf(w, __uint_as_float(d0[j] & 0xFFFF0000u), a[2 * j + 1]);
                a[8 + 2 * j] = fmaf(w, __uint_as_float(d1[j] << 16), a[8 + 2 * j]);
                a[9 + 2 * j] = fmaf(w, __uint_as_float(d1[j] & 0xFFFF0000u), a[9 + 2 * j]);
            }
        } else {
            const float* row = u2e + (long)vi * 64 + cl * 16;
            float4 v0 = *(const float4*)row;
            float4 v1 = *(const float4*)(row + 4);
            float4 v2 = *(const float4*)(row + 8);
            float4 v3 = *(const float4*)(row + 12);
            a[0] = fmaf(w, v0.x, a[0]);  a[1] = fmaf(w, v0.y, a[1]);
            a[2] = fmaf(w, v0.z, a[2]);  a[3] = fmaf(w, v0.w, a[3]);
            a[4] = fmaf(w, v1.x, a[4]);  a[5] = fmaf(w, v1.y, a[5]);
            a[6] = fmaf(w, v1.z, a[6]);  a[7] = fmaf(w, v1.w, a[7]);
            a[8] = fmaf(w, v2.x, a[8]);  a[9] = fmaf(w, v2.y, a[9]);
            a[10] = fmaf(w, v2.z, a[10]); a[11] = fmaf(w, v2.w, a[11]);
            a[12] = fmaf(w, v3.x, a[12]); a[13] = fmaf(w, v3.y, a[13]);
            a[14] = fmaf(w, v3.z, a[14]); a[15] = fmaf(w, v3.w, a[15]);
        }
    }
    // fold across the 16 slots (lane bits 2..5); cl dimension untouched
#pragma unroll
    for (int msk = 4; msk <= 32; msk <<= 1) {
        s += __shfl_xor(s, msk);
#pragma unroll
        for (int j = 0; j < 16; ++j) a[j] += __shfl_xor(a[j], msk);
    }
    if (slot == 0) {                // lanes 0..3: channels cl*16..cl*16+15
        float inv = 1.0f / fmaxf(s, 1e-9f);
        float* op = out + (long)n * 64 + cl * 16;
#pragma unroll
        for (int j = 0; j < 4; ++j) {
            float4 o = {a[4 * j] * inv, a[4 * j + 1] * inv,
                        a[4 * j + 2] * inv, a[4 * j + 3] * inv};
            *(float4*)(op + 4 * j) = o;
        }
    }
}

// ---------------- tier-3 fallback (tiny ws) -------------------------------------
__launch_bounds__(256)
__global__ void logits_fb_k(const int* __restrict__ nodes,
                            const int* __restrict__ neigh,
                            const int* __restrict__ segs,
                            const float* __restrict__ u2e,
                            const unsigned short* __restrict__ w1t,
                            const unsigned short* __restrict__ w2t,
                            const float* __restrict__ b1f, const float* __restrict__ b2f,
                            const float* __restrict__ w3f, const float* __restrict__ b3f,
                            float* __restrict__ ex, int E) {
    __shared__ __align__(16) unsigned short h1buf[4][16 * 72];
    const int wid = threadIdx.x >> 6;
    const int lane = threadIdx.x & 63;
    const int q = lane >> 4;
    const int m15 = lane & 15;
    const long base = ((long)blockIdx.x * 4 + wid) * 16;
    long ee0 = base + m15;
    int e = (int)(ee0 < E ? ee0 : (long)E - 1);
    int ni = neigh[e];
    int ctr = nodes[segs[e]];
    const float* eu = u2e + (long)ni * 64;
    const float* ur = u2e + (long)ctr * 64;
    bf16x8 a0 = cvt8(eu + q * 8), a1 = cvt8(eu + 32 + q * 8);
    bf16x8 a2 = cvt8(ur + q * 8), a3 = cvt8(ur + 32 + q * 8);
    f32x4 acc[4];
#pragma unroll
    for (int b = 0; b < 4; ++b) {
        float bvv = b1f[b * 16 + m15];
        acc[b] = (f32x4){bvv, bvv, bvv, bvv};
        const bf16x8* wrow = (const bf16x8*)(w1t + (b * 16 + m15) * 128);
        acc[b] = __builtin_amdgcn_mfma_f32_16x16x32_bf16(a0, wrow[0 + q], acc[b], 0, 0, 0);
        acc[b] = __builtin_amdgcn_mfma_f32_16x16x32_bf16(a1, wrow[4 + q], acc[b], 0, 0, 0);
        acc[b] = __builtin_amdgcn_mfma_f32_16x16x32_bf16(a2, wrow[8 + q], acc[b], 0, 0, 0);
        acc[b] = __builtin_amdgcn_mfma_f32_16x16x32_bf16(a3, wrow[12 + q], acc[b], 0, 0, 0);
    }
#pragma unroll
    for (int b = 0; b < 4; ++b)
#pragma unroll
        for (int r = 0; r < 4; ++r)
            h1buf[wid][(q * 4 + r) * 72 + b * 16 + m15] = f2bf(fmaxf(acc[b][r], 0.0f));
    const unsigned short* hrow = &h1buf[wid][m15 * 72];
    bf16x8 h0 = *(const bf16x8*)(hrow + q * 8);
    bf16x8 h1 = *(const bf16x8*)(hrow + 32 + q * 8);
    f32x4 acc2[4];
#pragma unroll
    for (int b = 0; b < 4; ++b) {
        float bvv = b2f[b * 16 + m15];
        acc2[b] = (f32x4){bvv, bvv, bvv, bvv};
        const bf16x8* wrow = (const bf16x8*)(w2t + (b * 16 + m15) * 64);
        acc2[b] = __builtin_amdgcn_mfma_f32_16x16x32_bf16(h0, wrow[0 + q], acc2[b], 0, 0, 0);
        acc2[b] = __builtin_amdgcn_mfma_f32_16x16x32_bf16(h1, wrow[4 + q], acc2[b], 0, 0, 0);
    }
    float b3v = b3f[0];
#pragma unroll
    for (int r = 0; r < 4; ++r) {
        float v = 0.0f;
#pragma unroll
        for (int b = 0; b < 4; ++b) v += fmaxf(acc2[b][r], 0.0f) * w3f[b * 16 + m15];
        v += __shfl_xor(v, 1);
        v += __shfl_xor(v, 2);
        v += __shfl_xor(v, 4);
        v += __shfl_xor(v, 8);
        long ee = base + q * 4 + r;
        if (m15 == r && ee < E) ex[ee] = __expf(v + b3v);
    }
}

extern "C" void kernel_launch(void* const* d_in, const int* in_sizes, int n_in,
                              void* d_out, int out_size, void* d_ws, size_t ws_size,
                              hipStream_t stream) {
    const int* nodes = (const int*)d_in[0];
    const int* neigh = (const int*)d_in[1];
    const int* segs  = (const int*)d_in[2];
    const float* u2e = (const float*)d_in[3];
    const float* w1  = (const float*)d_in[4];
    const float* b1  = (const float*)d_in[5];
    const float* w2  = (const float*)d_in[6];
    const float* b2  = (const float*)d_in[7];
    const float* w3  = (const float*)d_in[8];
    const float* b3  = (const float*)d_in[9];
    const int N = in_sizes[0];
    const int E = in_sizes[1];
    const long VD = in_sizes[3];
    const int V = (int)(VD / 64);

    char* ws = (char*)d_ws;
    size_t off = 0;
    auto alloc = [&](size_t bytes) { char* p = ws + off; off = (off + bytes + 255) & ~(size_t)255; return p; };
    float* ex = (float*)alloc((size_t)E * 4);
    int* seg_off = (int*)alloc((size_t)(N + 1) * 4);
    unsigned short* w1t = (unsigned short*)alloc(128 * 64 * 2);
    unsigned short* w2t = (unsigned short*)alloc(64 * 64 * 2);
    size_t need_min = off;
    unsigned short* Y = (unsigned short*)alloc((size_t)VD * 2);
    unsigned short* zb = (unsigned short*)alloc((size_t)N * 64 * 2);
    size_t need_t2 = off;
    unsigned short* u2ebf = (unsigned short*)alloc((size_t)VD * 2);
    size_t need_t1 = off;
    (void)need_min;

    float* out = (float*)d_out;

    const int pbblocks = 1 + (N + 256) / 256;
    prep_bounds_k<<<pbblocks, 256, 0, stream>>>(w1, w2, segs, w1t, w2t, seg_off, N, E);

    const int yblocks = ((V + 15) / 16 + 3) / 4;
    const int zblocks = ((N + 15) / 16 + 3) / 4;
    const int lblocks = ((E + 31) / 32 + 3) / 4;
    const int ablocks = (N + 3) / 4;

    if (ws_size >= need_t1) {
        conv_y_z_k<true><<<yblocks + zblocks, 256, 0, stream>>>(
            u2e, nodes, w1t, b1, u2ebf, Y, zb, V, N, yblocks);
        logits2_k<<<lblocks, 256, 0, stream>>>(neigh, segs, Y, zb, w2t, b2, w3, b3, ex, E);
        aggw_k<true><<<ablocks, 256, 0, stream>>>(seg_off, neigh, u2ebf, nullptr, ex, out, N);
    } else if (ws_size >= need_t2) {
        conv_y_z_k<false><<<yblocks + zblocks, 256, 0, stream>>>(
            u2e, nodes, w1t, b1, nullptr, Y, zb, V, N, yblocks);
        logits2_k<<<lblocks, 256, 0, stream>>>(neigh, segs, Y, zb, w2t, b2, w3, b3, ex, E);
        aggw_k<false><<<ablocks, 256, 0, stream>>>(seg_off, neigh, nullptr, u2e, ex, out, N);
    } else {
        const int blocks1 = ((E + 15) / 16 + 3) / 4;
        logits_fb_k<<<blocks1, 256, 0, stream>>>(nodes, neigh, segs, u2e, w1t, w2t,
                                                 b1, b2, w3, b3, ex, E);
        aggw_k<false><<<ablocks, 256, 0, stream>>>(seg_off, neigh, nullptr, u2e, ex, out, N);
    }
}

// Round 11
// 153.993 us; speedup vs baseline: 1.1830x; 1.1145x over previous
//
#include <hip/hip_runtime.h>
#include <hip/hip_bf16.h>

typedef __attribute__((ext_vector_type(8))) short bf16x8;
typedef __attribute__((ext_vector_type(4))) float f32x4;

__device__ __forceinline__ unsigned short f2bf(float f) {
    unsigned x = __float_as_uint(f);
    unsigned r = (x + 0x7FFF + ((x >> 16) & 1)) >> 16;   // RNE
    return (unsigned short)r;
}
__device__ __forceinline__ bf16x8 cvt8(const float* __restrict__ p) {
    bf16x8 r;
#pragma unroll
    for (int j = 0; j < 8; ++j) r[j] = (short)f2bf(p[j]);
    return r;
}
__device__ __forceinline__ unsigned pack_relu_bf16(unsigned yv, unsigned zv) {
    float lo = fmaxf(__uint_as_float(yv << 16) + __uint_as_float(zv << 16), 0.0f);
    float hi = fmaxf(__uint_as_float(yv & 0xFFFF0000u) + __uint_as_float(zv & 0xFFFF0000u), 0.0f);
    __hip_bfloat162 p = __float22bfloat162_rn(float2{lo, hi});
    return *(unsigned*)&p;
}

// ---------------- kernel B (all-in-one prep): grid sections ----------------------
// [0, yb)            : u2e->bf16 writeback + Y = u2e@W1_top   (W1 via per-block LDS)
// [yb, yb+zb)        : z[n] = u2e[nodes[n]]@W1_bot + b1       (W1 via per-block LDS)
// yb+zb              : w2t transpose (for logits2, launched later)
// (yb+zb, ...)       : seg_off binary search
// LDS W1: 64 rows x (128+8) cols bf16; pad 8 -> ds_read_b128 ~2-way banked (free).
template <bool BF>
__launch_bounds__(256)
__global__ void conv_all_k(const float* __restrict__ u2e,
                           const int* __restrict__ nodes,
                           const int* __restrict__ segs,
                           const float* __restrict__ w1,
                           const float* __restrict__ w2,
                           const float* __restrict__ b1f,
                           unsigned short* __restrict__ u2ebf,
                           unsigned short* __restrict__ Y,
                           unsigned short* __restrict__ z,
                           unsigned short* __restrict__ w2t,
                           int* __restrict__ seg_off,
                           int V, int N, int E, int yb, int zb) {
    __shared__ __align__(16) unsigned short w1l[64 * 136];
    const int bid = blockIdx.x;
    const int t = threadIdx.x;
    const int wid = t >> 6;
    const int lane = t & 63;
    const int q = lane >> 4;
    const int m15 = lane & 15;

    if (bid < yb + zb) {
        // cooperative W1 -> LDS (bf16, n-major rows, stride 136)
        for (int i = t; i < 128 * 64; i += 256) {
            int k = i >> 6, n = i & 63;
            w1l[n * 136 + k] = f2bf(w1[i]);
        }
        __syncthreads();

        if (bid < yb) {
            const int wbase = (bid * 4 + wid) * 16;
            if (wbase >= V) return;
            int row = min(wbase + m15, V - 1);
            const float* p = u2e + (long)row * 64;
            bf16x8 a0 = cvt8(p + q * 8);
            bf16x8 a1 = cvt8(p + 32 + q * 8);
            if (BF && wbase + m15 < V) {
                *(bf16x8*)(u2ebf + (long)row * 64 + q * 8) = a0;
                *(bf16x8*)(u2ebf + (long)row * 64 + 32 + q * 8) = a1;
            }
            f32x4 acc[4];
#pragma unroll
            for (int b = 0; b < 4; ++b) {
                acc[b] = (f32x4){0.f, 0.f, 0.f, 0.f};
                const unsigned short* wr = w1l + (b * 16 + m15) * 136;
                acc[b] = __builtin_amdgcn_mfma_f32_16x16x32_bf16(
                    a0, *(const bf16x8*)(wr + q * 8), acc[b], 0, 0, 0);
                acc[b] = __builtin_amdgcn_mfma_f32_16x16x32_bf16(
                    a1, *(const bf16x8*)(wr + 32 + q * 8), acc[b], 0, 0, 0);
            }
#pragma unroll
            for (int b = 0; b < 4; ++b)
#pragma unroll
                for (int r = 0; r < 4; ++r) {
                    int rr = wbase + q * 4 + r;
                    if (rr < V) Y[(long)rr * 64 + b * 16 + m15] = f2bf(acc[b][r]);
                }
        } else {
            const int wbase = ((bid - yb) * 4 + wid) * 16;
            if (wbase >= N) return;
            int nd = nodes[min(wbase + m15, N - 1)];
            const float* p = u2e + (long)nd * 64;
            bf16x8 a0 = cvt8(p + q * 8);
            bf16x8 a1 = cvt8(p + 32 + q * 8);
            f32x4 acc[4];
#pragma unroll
            for (int b = 0; b < 4; ++b) {
                float bv = b1f[b * 16 + m15];
                acc[b] = (f32x4){bv, bv, bv, bv};
                const unsigned short* wr = w1l + (b * 16 + m15) * 136;
                acc[b] = __builtin_amdgcn_mfma_f32_16x16x32_bf16(
                    a0, *(const bf16x8*)(wr + 64 + q * 8), acc[b], 0, 0, 0);
                acc[b] = __builtin_amdgcn_mfma_f32_16x16x32_bf16(
                    a1, *(const bf16x8*)(wr + 96 + q * 8), acc[b], 0, 0, 0);
            }
#pragma unroll
            for (int b = 0; b < 4; ++b)
#pragma unroll
                for (int r = 0; r < 4; ++r) {
                    int rr = wbase + q * 4 + r;
                    if (rr < N) z[(long)rr * 64 + b * 16 + m15] = f2bf(acc[b][r]);
                }
        }
    } else if (bid == yb + zb) {
        for (int i = t; i < 64 * 64; i += 256) {
            int k = i >> 6, n = i & 63;
            w2t[n * 64 + k] = f2bf(w2[i]);
        }
    } else {
        int idx = (bid - yb - zb - 1) * 256 + t;
        if (idx > N) return;
        int l = 0, r = E;
        while (l < r) { int mid = (l + r) >> 1; if (segs[mid] < idx) l = mid + 1; else r = mid; }
        seg_off[idx] = l;
    }
}

// ---------------- kernel 1: per-edge MLP, 32 edges/wave (2x16 groups) -----------
__launch_bounds__(256)
__global__ void logits2_k(const int* __restrict__ neigh,
                          const int* __restrict__ segs,
                          const unsigned short* __restrict__ Y,
                          const unsigned short* __restrict__ z,
                          const unsigned short* __restrict__ w2t,
                          const float* __restrict__ b2f,
                          const float* __restrict__ w3f, const float* __restrict__ b3f,
                          float* __restrict__ ex, int E) {
    const int wid = threadIdx.x >> 6;
    const int lane = threadIdx.x & 63;
    const int q = lane >> 4;
    const int m15 = lane & 15;
    const long base = ((long)blockIdx.x * 4 + wid) * 32;
    if (base >= E) return;

    int vi[2], sg[2];
#pragma unroll
    for (int g = 0; g < 2; ++g) {
        long e = base + g * 16 + m15;
        int ec = (int)(e < E ? e : (long)E - 1);
        vi[g] = neigh[ec];
        sg[g] = segs[ec];
    }
    bf16x8 y0[2], y1[2], zz0[2], zz1[2];
#pragma unroll
    for (int g = 0; g < 2; ++g) {
        const unsigned short* yr = Y + (long)vi[g] * 64;
        y0[g] = *(const bf16x8*)(yr + q * 8);
        y1[g] = *(const bf16x8*)(yr + 32 + q * 8);
        const unsigned short* zr = z + (long)sg[g] * 64;
        zz0[g] = *(const bf16x8*)(zr + q * 8);
        zz1[g] = *(const bf16x8*)(zr + 32 + q * 8);
    }

    f32x4 acc[2][4];
#pragma unroll
    for (int g = 0; g < 2; ++g) {
        bf16x8 h0, h1;
#pragma unroll
        for (int j = 0; j < 4; ++j) {
            ((unsigned*)&h0)[j] = pack_relu_bf16(((unsigned*)&y0[g])[j], ((unsigned*)&zz0[g])[j]);
            ((unsigned*)&h1)[j] = pack_relu_bf16(((unsigned*)&y1[g])[j], ((unsigned*)&zz1[g])[j]);
        }
#pragma unroll
        for (int b = 0; b < 4; ++b) {
            float bv = b2f[b * 16 + m15];
            acc[g][b] = (f32x4){bv, bv, bv, bv};
            const bf16x8* wrow = (const bf16x8*)(w2t + (b * 16 + m15) * 64);
            acc[g][b] = __builtin_amdgcn_mfma_f32_16x16x32_bf16(h0, wrow[0 + q], acc[g][b], 0, 0, 0);
            acc[g][b] = __builtin_amdgcn_mfma_f32_16x16x32_bf16(h1, wrow[4 + q], acc[g][b], 0, 0, 0);
        }
    }

    const float b3v = b3f[0];
#pragma unroll
    for (int g = 0; g < 2; ++g)
#pragma unroll
        for (int r = 0; r < 4; ++r) {
            float v = 0.0f;
#pragma unroll
            for (int b = 0; b < 4; ++b) v += fmaxf(acc[g][b][r], 0.0f) * w3f[b * 16 + m15];
            v += __shfl_xor(v, 1);
            v += __shfl_xor(v, 2);
            v += __shfl_xor(v, 4);
            v += __shfl_xor(v, 8);
            long ee = base + g * 16 + q * 4 + r;
            if (m15 == r && ee < E) ex[ee] = __expf(v + b3v);
        }
}

// ---------------- kernel 2: wave-per-node weighted segment sum (R7 8-slot) ------
// lane = slot(0..7)*8 + cl(0..7); slot -> edge stride 8, cl -> 8 channels (16B).
template <bool BF>
__launch_bounds__(256)
__global__ void aggw_k(const int* __restrict__ seg_off,
                       const int* __restrict__ neigh,
                       const unsigned short* __restrict__ u2ebf,
                       const float* __restrict__ u2e,
                       const float* __restrict__ ex,
                       float* __restrict__ out, int N) {
    const int wid = threadIdx.x >> 6;
    const int lane = threadIdx.x & 63;
    const int n = blockIdx.x * 4 + wid;
    if (n >= N) return;
    const int lo = seg_off[n];
    const int hi = seg_off[n + 1];
    const int slot = lane >> 3;
    const int cl = lane & 7;

    float a[8] = {0.f, 0.f, 0.f, 0.f, 0.f, 0.f, 0.f, 0.f};
    float s = 0.0f;

    for (int e = lo + slot; e < hi; e += 8) {
        float w = ex[e];
        int vi = neigh[e];
        s += w;
        if constexpr (BF) {
            bf16x8 v = *(const bf16x8*)(u2ebf + (long)vi * 64 + cl * 8);
            const unsigned* vd = (const unsigned*)&v;
#pragma unroll
            for (int j = 0; j < 4; ++j) {
                a[2 * j]     = fmaf(w, __uint_as_float(vd[j] << 16), a[2 * j]);
                a[2 * j + 1] = fmaf(w, __uint_as_float(vd[j] & 0xFFFF0000u), a[2 * j + 1]);
            }
        } else {
            const float* row = u2e + (long)vi * 64 + cl * 8;
            float4 v0 = *(const float4*)row;
            float4 v1 = *(const float4*)(row + 4);
            a[0] = fmaf(w, v0.x, a[0]); a[1] = fmaf(w, v0.y, a[1]);
            a[2] = fmaf(w, v0.z, a[2]); a[3] = fmaf(w, v0.w, a[3]);
            a[4] = fmaf(w, v1.x, a[4]); a[5] = fmaf(w, v1.y, a[5]);
            a[6] = fmaf(w, v1.z, a[6]); a[7] = fmaf(w, v1.w, a[7]);
        }
    }
#pragma unroll
    for (int msk = 8; msk <= 32; msk <<= 1) {
        s += __shfl_xor(s, msk);
#pragma unroll
        for (int j = 0; j < 8; ++j) a[j] += __shfl_xor(a[j], msk);
    }
    if (slot == 0) {
        float inv = 1.0f / fmaxf(s, 1e-9f);
        float4 o0 = {a[0] * inv, a[1] * inv, a[2] * inv, a[3] * inv};
        float4 o1 = {a[4] * inv, a[5] * inv, a[6] * inv, a[7] * inv};
        float* op = out + (long)n * 64 + cl * 8;
        *(float4*)op = o0;
        *(float4*)(op + 4) = o1;
    }
}

// ---------------- tier-3 fallback (tiny ws) -------------------------------------
__global__ void prep_bounds_k(const float* __restrict__ w1,
                              const float* __restrict__ w2,
                              const int* __restrict__ segs,
                              unsigned short* __restrict__ w1t,
                              unsigned short* __restrict__ w2t,
                              int* __restrict__ seg_off, int N, int E) {
    int t = threadIdx.x;
    if (blockIdx.x == 0) {
        for (int i = t; i < 128 * 64; i += 256) {
            int k = i >> 6, n = i & 63;
            w1t[n * 128 + k] = f2bf(w1[i]);
        }
        for (int i = t; i < 64 * 64; i += 256) {
            int k = i >> 6, n = i & 63;
            w2t[n * 64 + k] = f2bf(w2[i]);
        }
    } else {
        int idx = (blockIdx.x - 1) * 256 + t;
        if (idx > N) return;
        int l = 0, r = E;
        while (l < r) { int mid = (l + r) >> 1; if (segs[mid] < idx) l = mid + 1; else r = mid; }
        seg_off[idx] = l;
    }
}

__launch_bounds__(256)
__global__ void logits_fb_k(const int* __restrict__ nodes,
                            const int* __restrict__ neigh,
                            const int* __restrict__ segs,
                            const float* __restrict__ u2e,
                            const unsigned short* __restrict__ w1t,
                            const unsigned short* __restrict__ w2t,
                            const float* __restrict__ b1f, const float* __restrict__ b2f,
                            const float* __restrict__ w3f, const float* __restrict__ b3f,
                            float* __restrict__ ex, int E) {
    __shared__ __align__(16) unsigned short h1buf[4][16 * 72];
    const int wid = threadIdx.x >> 6;
    const int lane = threadIdx.x & 63;
    const int q = lane >> 4;
    const int m15 = lane & 15;
    const long base = ((long)blockIdx.x * 4 + wid) * 16;
    long ee0 = base + m15;
    int e = (int)(ee0 < E ? ee0 : (long)E - 1);
    int ni = neigh[e];
    int ctr = nodes[segs[e]];
    const float* eu = u2e + (long)ni * 64;
    const float* ur = u2e + (long)ctr * 64;
    bf16x8 a0 = cvt8(eu + q * 8), a1 = cvt8(eu + 32 + q * 8);
    bf16x8 a2 = cvt8(ur + q * 8), a3 = cvt8(ur + 32 + q * 8);
    f32x4 acc[4];
#pragma unroll
    for (int b = 0; b < 4; ++b) {
        float bvv = b1f[b * 16 + m15];
        acc[b] = (f32x4){bvv, bvv, bvv, bvv};
        const bf16x8* wrow = (const bf16x8*)(w1t + (b * 16 + m15) * 128);
        acc[b] = __builtin_amdgcn_mfma_f32_16x16x32_bf16(a0, wrow[0 + q], acc[b], 0, 0, 0);
        acc[b] = __builtin_amdgcn_mfma_f32_16x16x32_bf16(a1, wrow[4 + q], acc[b], 0, 0, 0);
        acc[b] = __builtin_amdgcn_mfma_f32_16x16x32_bf16(a2, wrow[8 + q], acc[b], 0, 0, 0);
        acc[b] = __builtin_amdgcn_mfma_f32_16x16x32_bf16(a3, wrow[12 + q], acc[b], 0, 0, 0);
    }
#pragma unroll
    for (int b = 0; b < 4; ++b)
#pragma unroll
        for (int r = 0; r < 4; ++r)
            h1buf[wid][(q * 4 + r) * 72 + b * 16 + m15] = f2bf(fmaxf(acc[b][r], 0.0f));
    const unsigned short* hrow = &h1buf[wid][m15 * 72];
    bf16x8 h0 = *(const bf16x8*)(hrow + q * 8);
    bf16x8 h1 = *(const bf16x8*)(hrow + 32 + q * 8);
    f32x4 acc2[4];
#pragma unroll
    for (int b = 0; b < 4; ++b) {
        float bvv = b2f[b * 16 + m15];
        acc2[b] = (f32x4){bvv, bvv, bvv, bvv};
        const bf16x8* wrow = (const bf16x8*)(w2t + (b * 16 + m15) * 64);
        acc2[b] = __builtin_amdgcn_mfma_f32_16x16x32_bf16(h0, wrow[0 + q], acc2[b], 0, 0, 0);
        acc2[b] = __builtin_amdgcn_mfma_f32_16x16x32_bf16(h1, wrow[4 + q], acc2[b], 0, 0, 0);
    }
    float b3v = b3f[0];
#pragma unroll
    for (int r = 0; r < 4; ++r) {
        float v = 0.0f;
#pragma unroll
        for (int b = 0; b < 4; ++b) v += fmaxf(acc2[b][r], 0.0f) * w3f[b * 16 + m15];
        v += __shfl_xor(v, 1);
        v += __shfl_xor(v, 2);
        v += __shfl_xor(v, 4);
        v += __shfl_xor(v, 8);
        long ee = base + q * 4 + r;
        if (m15 == r && ee < E) ex[ee] = __expf(v + b3v);
    }
}

extern "C" void kernel_launch(void* const* d_in, const int* in_sizes, int n_in,
                              void* d_out, int out_size, void* d_ws, size_t ws_size,
                              hipStream_t stream) {
    const int* nodes = (const int*)d_in[0];
    const int* neigh = (const int*)d_in[1];
    const int* segs  = (const int*)d_in[2];
    const float* u2e = (const float*)d_in[3];
    const float* w1  = (const float*)d_in[4];
    const float* b1  = (const float*)d_in[5];
    const float* w2  = (const float*)d_in[6];
    const float* b2  = (const float*)d_in[7];
    const float* w3  = (const float*)d_in[8];
    const float* b3  = (const float*)d_in[9];
    const int N = in_sizes[0];
    const int E = in_sizes[1];
    const long VD = in_sizes[3];
    const int V = (int)(VD / 64);

    char* ws = (char*)d_ws;
    size_t off = 0;
    auto alloc = [&](size_t bytes) { char* p = ws + off; off = (off + bytes + 255) & ~(size_t)255; return p; };
    float* ex = (float*)alloc((size_t)E * 4);
    int* seg_off = (int*)alloc((size_t)(N + 1) * 4);
    unsigned short* w1t = (unsigned short*)alloc(128 * 64 * 2);   // tier-3 only
    unsigned short* w2t = (unsigned short*)alloc(64 * 64 * 2);
    size_t need_min = off;
    unsigned short* Y = (unsigned short*)alloc((size_t)VD * 2);
    unsigned short* zb = (unsigned short*)alloc((size_t)N * 64 * 2);
    size_t need_t2 = off;
    unsigned short* u2ebf = (unsigned short*)alloc((size_t)VD * 2);
    size_t need_t1 = off;
    (void)need_min;

    float* out = (float*)d_out;

    const int yb = ((V + 15) / 16 + 3) / 4;
    const int zbk = ((N + 15) / 16 + 3) / 4;
    const int bblocks = (N + 256) / 256;
    const int lblocks = ((E + 31) / 32 + 3) / 4;
    const int ablocks = (N + 3) / 4;

    if (ws_size >= need_t1) {
        conv_all_k<true><<<yb + zbk + 1 + bblocks, 256, 0, stream>>>(
            u2e, nodes, segs, w1, w2, b1, u2ebf, Y, zb, w2t, seg_off, V, N, E, yb, zbk);
        logits2_k<<<lblocks, 256, 0, stream>>>(neigh, segs, Y, zb, w2t, b2, w3, b3, ex, E);
        aggw_k<true><<<ablocks, 256, 0, stream>>>(seg_off, neigh, u2ebf, nullptr, ex, out, N);
    } else if (ws_size >= need_t2) {
        conv_all_k<false><<<yb + zbk + 1 + bblocks, 256, 0, stream>>>(
            u2e, nodes, segs, w1, w2, b1, nullptr, Y, zb, w2t, seg_off, V, N, E, yb, zbk);
        logits2_k<<<lblocks, 256, 0, stream>>>(neigh, segs, Y, zb, w2t, b2, w3, b3, ex, E);
        aggw_k<false><<<ablocks, 256, 0, stream>>>(seg_off, neigh, nullptr, u2e, ex, out, N);
    } else {
        const int pbblocks = 1 + (N + 256) / 256;
        prep_bounds_k<<<pbblocks, 256, 0, stream>>>(w1, w2, segs, w1t, w2t, seg_off, N, E);
        const int blocks1 = ((E + 15) / 16 + 3) / 4;
        logits_fb_k<<<blocks1, 256, 0, stream>>>(nodes, neigh, segs, u2e, w1t, w2t,
                                                 b1, b2, w3, b3, ex, E);
        aggw_k<false><<<ablocks, 256, 0, stream>>>(seg_off, neigh, nullptr, u2e, ex, out, N);
    }
}